// Round 14
// baseline (261.471 us; speedup 1.0000x reference)
//
#include <hip/hip_runtime.h>
#include <hip/hip_bf16.h>

#define B_  8
#define C_  512
#define T_  1024
#define NH_ 8
#define HD_ 64

// exp(S) computed as exp2(S*log2e); log2e folded into Wq/bq scale.
#define QSCALE 0.1803368801111243f   // 0.125 * log2(e)

using short8 = __attribute__((ext_vector_type(8))) short;
using f32x4  = __attribute__((ext_vector_type(4))) float;
using f32x16 = __attribute__((ext_vector_type(16))) float;
using us4    = __attribute__((ext_vector_type(4))) unsigned short;

__device__ __forceinline__ unsigned short f2bf(float f) {
    unsigned u = __builtin_bit_cast(unsigned, f);
    u += 0x7fff + ((u >> 16) & 1);
    return (unsigned short)(u >> 16);
}
__device__ __forceinline__ unsigned pack2bf(float lo, float hi) {
    __hip_bfloat162 h = __float22bfloat162_rn(float2{lo, hi});
    unsigned u;
    __builtin_memcpy(&u, &h, 4);
    return u;
}

// async global->LDS, 16B per lane. LDS dest = wave-uniform base + lane*16.
__device__ __forceinline__ void gload_lds16(const ushort* g, ushort* l) {
    __builtin_amdgcn_global_load_lds(
        (const __attribute__((address_space(1))) void*)g,
        (__attribute__((address_space(3))) void*)l, 16, 0, 0);
}

// counted vmcnt wait + scheduling fence (rule 18)
template <int N>
__device__ __forceinline__ void wait_vmcnt() {
    asm volatile("s_waitcnt vmcnt(%0)" ::"n"(N) : "memory");
    __builtin_amdgcn_sched_barrier(0);
}
__device__ __forceinline__ void barrier_raw() {
    __builtin_amdgcn_sched_barrier(0);
    __builtin_amdgcn_s_barrier();
}

// ---------------- K0: fused prep — x transpose + W transposes ----------------
__global__ __launch_bounds__(256) void k_prep(const float* __restrict__ x,
                                              const float* __restrict__ Wq,
                                              const float* __restrict__ Wk,
                                              const float* __restrict__ Wv,
                                              const float* __restrict__ Wo,
                                              ushort* __restrict__ xt,
                                              ushort* __restrict__ Wqkvt,
                                              ushort* __restrict__ Wot) {
    __shared__ float tile[32][33];
    int L = blockIdx.x;
    int tx = threadIdx.x & 31, ty = threadIdx.x >> 5;
    if (L < 4096) {
        int b = L >> 9, rem = L & 511;
        int t0 = (rem & 31) * 32, c0 = (rem >> 5) * 32;
#pragma unroll
        for (int i = 0; i < 4; i++)
            tile[ty + i * 8][tx] = x[((size_t)b * C_ + c0 + ty + i * 8) * T_ + t0 + tx];
        __syncthreads();
#pragma unroll
        for (int i = 0; i < 4; i++)
            xt[((size_t)b * T_ + t0 + ty + i * 8) * C_ + c0 + tx] = f2bf(tile[tx][ty + i * 8]);
    } else {
        int LL = L - 4096;
        int m = LL >> 8, rem = LL & 255;
        int k0 = (rem & 15) * 32, n0 = (rem >> 4) * 32;
        const float* W = (m == 0) ? Wq : (m == 1) ? Wk : (m == 2) ? Wv : Wo;
        ushort* dst = (m < 3) ? (Wqkvt + (size_t)m * C_ * C_) : Wot;
        float scale = (m == 0) ? QSCALE : 1.0f;
#pragma unroll
        for (int i = 0; i < 4; i++)
            tile[ty + i * 8][tx] = W[(size_t)(k0 + ty + i * 8) * C_ + n0 + tx];
        __syncthreads();
#pragma unroll
        for (int i = 0; i < 4; i++)
            dst[(size_t)(n0 + ty + i * 8) * C_ + k0 + tx] = f2bf(tile[tx][ty + i * 8] * scale);
    }
}

// ---------------- GEMM mainloop: C[128x128] = A[128xK] * Bt[128xK]^T ----------------
__device__ __forceinline__ void gemm_core(const ushort* __restrict__ A,
                                          const ushort* __restrict__ Bt,
                                          int row0, int col0, int tid,
                                          ushort (*As)[8192], ushort (*Bs)[8192],
                                          f32x4 acc[4][4]) {
    f32x4 zero = {0.f, 0.f, 0.f, 0.f};
#pragma unroll
    for (int i = 0; i < 4; i++)
#pragma unroll
        for (int j = 0; j < 4; j++) acc[i][j] = zero;
    int lane = tid & 63, w = tid >> 6;
    int ql = lane & 15, g = lane >> 4;
    int wm = (w >> 1) * 64, wn = (w & 1) * 64;
    int srow = lane >> 3;
    int scol8 = (lane & 7) ^ (srow & 7);

#pragma unroll
    for (int i = 0; i < 4; i++) {
        int c = w * 4 + i;
        int r = c * 8 + srow;
        gload_lds16(A + (size_t)(row0 + r) * C_ + scol8 * 8, As[0] + c * 512);
        gload_lds16(Bt + (size_t)(col0 + r) * C_ + scol8 * 8, Bs[0] + c * 512);
    }

#pragma unroll
    for (int kt = 0; kt < 8; kt++) {
        int cur = kt & 1;
        if (kt < 7) {
            int k0 = (kt + 1) * 64;
#pragma unroll
            for (int i = 0; i < 4; i++) {
                int c = w * 4 + i;
                int r = c * 8 + srow;
                gload_lds16(A + (size_t)(row0 + r) * C_ + k0 + scol8 * 8, As[cur ^ 1] + c * 512);
                gload_lds16(Bt + (size_t)(col0 + r) * C_ + k0 + scol8 * 8, Bs[cur ^ 1] + c * 512);
            }
            wait_vmcnt<8>();
        } else {
            wait_vmcnt<0>();
        }
        barrier_raw();
        const ushort* Ac = As[cur];
        const ushort* Bc = Bs[cur];
        __builtin_amdgcn_s_setprio(1);
#pragma unroll
        for (int s = 0; s < 2; s++) {
            short8 a[4], b[4];
            int cs = ((4 * s + g) ^ (ql & 7)) * 8;
#pragma unroll
            for (int mt = 0; mt < 4; mt++)
                a[mt] = *(const short8*)(Ac + (wm + mt * 16 + ql) * 64 + cs);
#pragma unroll
            for (int nt = 0; nt < 4; nt++)
                b[nt] = *(const short8*)(Bc + (wn + nt * 16 + ql) * 64 + cs);
#pragma unroll
            for (int mt = 0; mt < 4; mt++)
#pragma unroll
                for (int nt = 0; nt < 4; nt++)
                    acc[mt][nt] = __builtin_amdgcn_mfma_f32_16x16x32_bf16(
                        a[mt], b[nt], acc[mt][nt], 0, 0, 0);
        }
        __builtin_amdgcn_s_setprio(0);
        barrier_raw();
    }
}

// ---------------- K1: QKV projection, LDS-bounce epilogue ----------------
__global__ __launch_bounds__(256) void k_qkv(const ushort* __restrict__ xt,
                                             const ushort* __restrict__ Wqkvt,
                                             const float* __restrict__ bq,
                                             const float* __restrict__ bk,
                                             const float* __restrict__ bv,
                                             ushort* __restrict__ Qh,
                                             ushort* __restrict__ Kh,
                                             ushort* __restrict__ Vt) {
    __shared__ __align__(16) ushort As[2][8192];
    __shared__ __align__(16) ushort Bs[2][8192];
    f32x4 acc[4][4];
    int tid = threadIdx.x;
    int L = blockIdx.x;
    int n = L >> 3, xcd = L & 7;
    int row0 = (xcd * 8 + (n & 7)) * 128;
    int col0 = (n >> 3) * 128;
    gemm_core(xt, Wqkvt, row0, col0, tid, As, Bs, acc);
    int lane = tid & 63, w = tid >> 6;
    int ql = lane & 15, g = lane >> 4;
    int wm = (w >> 1) * 64, wn = (w & 1) * 64;
    int which = col0 >> 9;  // 0=Q 1=K 2=V
    const float* bias = (which == 0) ? bq : (which == 1) ? bk : bv;
    float bscale = (which == 0) ? QSCALE : 1.0f;
    ushort* Lt = &As[0][0];  // 32KB bounce tile (gemm LDS dead)

    if (which != 2) {
        ushort* dst = (which == 0) ? Qh : Kh;
#pragma unroll
        for (int mt = 0; mt < 4; mt++)
#pragma unroll
            for (int nt = 0; nt < 4; nt++) {
                int col = wn + nt * 16 + ql;
                float bsv = bias[(col0 + col) & 511] * bscale;
#pragma unroll
                for (int r = 0; r < 4; r++) {
                    int row = wm + mt * 16 + 4 * g + r;
                    int sw = col ^ ((row & 7) << 3);
                    Lt[row * 128 + sw] = f2bf(acc[mt][nt][r] + bsv);
                }
            }
        __syncthreads();
#pragma unroll
        for (int i = 0; i < 8; i++) {
            int task = w * 512 + i * 64 + lane;
            int row = task >> 4, gran = task & 15;
            int sg = gran ^ (row & 7);
            short8 vle = *(const short8*)(Lt + row * 128 + sg * 8);
            int gcol = col0 + gran * 8;
            int hc = gcol & 511, h = hc >> 6, d = hc & 63;
            int grow = row0 + row, b = grow >> 10, t = grow & 1023;
            *(short8*)(dst + ((size_t)(b * NH_ + h) * T_ + t) * HD_ + d) = vle;
        }
    } else {
#pragma unroll
        for (int mt = 0; mt < 4; mt++)
#pragma unroll
            for (int nt = 0; nt < 4; nt++) {
                int col = wn + nt * 16 + ql;
                float bsv = bias[(col0 + col) & 511] * bscale;
                int rowb = wm + mt * 16 + 4 * g;
                int swz = (rowb >> 2) ^ (col & 31);
                us4 pk;
#pragma unroll
                for (int r = 0; r < 4; r++) pk[r] = f2bf(acc[mt][nt][r] + bsv);
                *(us4*)(Lt + col * 128 + swz * 4) = pk;
            }
        __syncthreads();
#pragma unroll
        for (int i = 0; i < 8; i++) {
            int task = w * 512 + i * 64 + lane;
            int colr = task >> 4, gran = task & 15;
            int g4a = (2 * gran) ^ (colr & 31);
            int g4b = (2 * gran + 1) ^ (colr & 31);
            us4 lo = *(const us4*)(Lt + colr * 128 + g4a * 4);
            us4 hi4 = *(const us4*)(Lt + colr * 128 + g4b * 4);
            us4 arr[2] = {lo, hi4};
            short8 vle;
            __builtin_memcpy(&vle, arr, 16);
            int gcol = col0 + colr;
            int hc = gcol & 511, h = hc >> 6, d = hc & 63;
            int grow = row0 + gran * 8, b = grow >> 10, t = grow & 1023;
            *(short8*)(Vt + ((size_t)(b * NH_ + h) * HD_ + d) * T_ + t) = vle;
        }
    }
}

// ---------------- K2: flash attention, 64 q-rows/wave ----------------
// QBLK=256, 4 waves x 64 q-rows, grid 256 (1 block/CU -> VGPR-unconstrained).
// Each K/V fragment read once per wave feeds TWO q-halves (A/B) -> LDS
// read bytes per q-row halved. 4-slot pipeline, depth 2, one barrier/tile.
__global__ void k_attn(const ushort* __restrict__ Qh,
                       const ushort* __restrict__ Kh,
                       const ushort* __restrict__ Vt,
                       ushort* __restrict__ Y) {
    __shared__ __align__(16) ushort KV[8][4096];  // K slots 0-3, V slots 4-7
    int tid = threadIdx.x, lane = tid & 63, w = tid >> 6;
    int hi = lane >> 5, l31 = lane & 31, l7 = lane & 7;
    int bh = blockIdx.x & 63, q0 = (blockIdx.x >> 6) * 256;
    int b = bh >> 3, h = bh & 7;
    int srow = lane >> 3;
    int scol8 = l7 ^ (srow & 7);
    const ushort* Kbase = Kh + (size_t)bh * T_ * HD_;
    const ushort* Vbase = Vt + (size_t)bh * HD_ * T_;
    const ushort* kv = &KV[0][0];

    // two q-halves per wave: rows q0 + w*64 + [0,32) and [32,64)
    short8 qaA[4], qaB[4];
#pragma unroll
    for (int s = 0; s < 4; s++) {
        size_t rbase = (size_t)bh * T_ + q0 + w * 64 + l31;
        qaA[s] = *(const short8*)(Qh + rbase * HD_ + s * 16 + hi * 8);
        qaB[s] = *(const short8*)(Qh + (rbase + 32) * HD_ + s * 16 + hi * 8);
    }

    int fofs[4];
#pragma unroll
    for (int s = 0; s < 4; s++) fofs[s] = ((2 * s + hi) ^ l7) * 8;
    int rowlo = l31 * 64;

    short8 ones;
    {
        short ov = (l31 == 0) ? (short)0x3F80 : (short)0;
#pragma unroll
        for (int j = 0; j < 8; j++) ones[j] = ov;
    }

    f32x16 o0a, o1a, o0b, o1b, o5a, o5b, z16;
#pragma unroll
    for (int i = 0; i < 16; i++) {
        o0a[i] = 0.f; o1a[i] = 0.f; o0b[i] = 0.f; o1b[i] = 0.f;
        o5a[i] = 0.f; o5b[i] = 0.f; z16[i] = 0.f;
    }

    // prologue: tiles 0,1 -> slots 0,1
#pragma unroll
    for (int tt = 0; tt < 2; tt++) {
#pragma unroll
        for (int i = 0; i < 2; i++) {
            int c = w * 2 + i;
            int r = c * 8 + srow;
            gload_lds16(Kbase + (size_t)(tt * 64 + r) * HD_ + scol8 * 8,
                        &KV[tt][0] + c * 512);
            gload_lds16(Vbase + (size_t)r * T_ + tt * 64 + scol8 * 8,
                        &KV[4 + tt][0] + c * 512);
        }
    }

#pragma unroll
    for (int t = 0; t < 16; t++) {
        const int sl = t & 3;
        if (t < 14) {
            const int ds = (t + 2) & 3;
            int kv0 = (t + 2) * 64;
#pragma unroll
            for (int i = 0; i < 2; i++) {
                int c = w * 2 + i;
                int r = c * 8 + srow;
                gload_lds16(Kbase + (size_t)(kv0 + r) * HD_ + scol8 * 8,
                            &KV[ds][0] + c * 512);
                gload_lds16(Vbase + (size_t)r * T_ + kv0 + scol8 * 8,
                            &KV[4 + ds][0] + c * 512);
            }
            wait_vmcnt<8>();
        } else if (t == 14) {
            wait_vmcnt<4>();
        } else {
            wait_vmcnt<0>();
        }
        barrier_raw();

        // S^T[k][q]: each ka pair feeds both q-halves
        f32x16 sTa0, sTa1, sTb0, sTb1;
        __builtin_amdgcn_s_setprio(1);
        {
            short8 ka0 = *(const short8*)(kv + sl * 4096 + rowlo + fofs[0]);
            short8 ka1 = *(const short8*)(kv + sl * 4096 + 2048 + rowlo + fofs[0]);
            sTa0 = __builtin_amdgcn_mfma_f32_32x32x16_bf16(ka0, qaA[0], z16, 0, 0, 0);
            sTa1 = __builtin_amdgcn_mfma_f32_32x32x16_bf16(ka1, qaA[0], z16, 0, 0, 0);
            sTb0 = __builtin_amdgcn_mfma_f32_32x32x16_bf16(ka0, qaB[0], z16, 0, 0, 0);
            sTb1 = __builtin_amdgcn_mfma_f32_32x32x16_bf16(ka1, qaB[0], z16, 0, 0, 0);
        }
#pragma unroll
        for (int s = 1; s < 4; s++) {
            short8 ka0 = *(const short8*)(kv + sl * 4096 + rowlo + fofs[s]);
            short8 ka1 = *(const short8*)(kv + sl * 4096 + 2048 + rowlo + fofs[s]);
            sTa0 = __builtin_amdgcn_mfma_f32_32x32x16_bf16(ka0, qaA[s], sTa0, 0, 0, 0);
            sTa1 = __builtin_amdgcn_mfma_f32_32x32x16_bf16(ka1, qaA[s], sTa1, 0, 0, 0);
            sTb0 = __builtin_amdgcn_mfma_f32_32x32x16_bf16(ka0, qaB[s], sTb0, 0, 0, 0);
            sTb1 = __builtin_amdgcn_mfma_f32_32x32x16_bf16(ka1, qaB[s], sTb1, 0, 0, 0);
        }
        __builtin_amdgcn_s_setprio(0);

        // P = exp2(S), pack bf16 pairs
        unsigned pkva0[8], pkva1[8], pkvb0[8], pkvb1[8];
#pragma unroll
        for (int i = 0; i < 8; i++) {
            pkva0[i] = pack2bf(__builtin_amdgcn_exp2f(sTa0[2 * i]),
                               __builtin_amdgcn_exp2f(sTa0[2 * i + 1]));
            pkva1[i] = pack2bf(__builtin_amdgcn_exp2f(sTa1[2 * i]),
                               __builtin_amdgcn_exp2f(sTa1[2 * i + 1]));
            pkvb0[i] = pack2bf(__builtin_amdgcn_exp2f(sTb0[2 * i]),
                               __builtin_amdgcn_exp2f(sTb0[2 * i + 1]));
            pkvb1[i] = pack2bf(__builtin_amdgcn_exp2f(sTb1[2 * i]),
                               __builtin_amdgcn_exp2f(sTb1[2 * i + 1]));
        }

        // PV + ones-lsum: each vb pair feeds both q-halves
        __builtin_amdgcn_s_setprio(1);
#pragma unroll
        for (int t4 = 0; t4 < 4; t4++) {
            const int h2 = t4 & 1;
            unsigned a0, a1, a2, a3, b0, b1, b2, b3;
            if (t4 < 2) {
                a0 = pkva0[4 * h2 + 0]; a2 = pkva0[4 * h2 + 2];
                a1 = pkva0[4 * h2 + 1]; a3 = pkva0[4 * h2 + 3];
                b0 = pkvb0[4 * h2 + 0]; b2 = pkvb0[4 * h2 + 2];
                b1 = pkvb0[4 * h2 + 1]; b3 = pkvb0[4 * h2 + 3];
            } else {
                a0 = pkva1[4 * h2 + 0]; a2 = pkva1[4 * h2 + 2];
                a1 = pkva1[4 * h2 + 1]; a3 = pkva1[4 * h2 + 3];
                b0 = pkvb1[4 * h2 + 0]; b2 = pkvb1[4 * h2 + 2];
                b1 = pkvb1[4 * h2 + 1]; b3 = pkvb1[4 * h2 + 3];
            }
            asm("v_permlane32_swap_b32 %0, %1" : "+v"(a0), "+v"(a2));
            asm("v_permlane32_swap_b32 %0, %1" : "+v"(a1), "+v"(a3));
            asm("v_permlane32_swap_b32 %0, %1" : "+v"(b0), "+v"(b2));
            asm("v_permlane32_swap_b32 %0, %1" : "+v"(b1), "+v"(b3));
            unsigned auA[4] = {a0, a1, a2, a3};
            unsigned auB[4] = {b0, b1, b2, b3};
            short8 paA, paB;
            __builtin_memcpy(&paA, auA, 16);
            __builtin_memcpy(&paB, auB, 16);
            short8 vb0 = *(const short8*)(kv + (4 + sl) * 4096 + rowlo + fofs[t4]);
            short8 vb1 = *(const short8*)(kv + (4 + sl) * 4096 + 2048 + rowlo + fofs[t4]);
            o0a = __builtin_amdgcn_mfma_f32_32x32x16_bf16(paA, vb0, o0a, 0, 0, 0);
            o1a = __builtin_amdgcn_mfma_f32_32x32x16_bf16(paA, vb1, o1a, 0, 0, 0);
            o0b = __builtin_amdgcn_mfma_f32_32x32x16_bf16(paB, vb0, o0b, 0, 0, 0);
            o1b = __builtin_amdgcn_mfma_f32_32x32x16_bf16(paB, vb1, o1b, 0, 0, 0);
            o5a = __builtin_amdgcn_mfma_f32_32x32x16_bf16(paA, ones, o5a, 0, 0, 0);
            o5b = __builtin_amdgcn_mfma_f32_32x32x16_bf16(paB, ones, o5b, 0, 0, 0);
        }
        __builtin_amdgcn_s_setprio(0);
        // no second barrier: slot reuse distance (4) > prefetch depth (2)
    }

#pragma unroll
    for (int r = 0; r < 16; r++) {
        int qr = (r & 3) + 8 * (r >> 2) + 4 * hi;
        float liA = 1.0f / __shfl(o5a[r], hi * 32);
        float liB = 1.0f / __shfl(o5b[r], hi * 32);
        int trowA = q0 + w * 64 + qr;
        size_t baseA = ((size_t)b * T_ + trowA) * C_ + h * HD_;
        Y[baseA + l31] = f2bf(o0a[r] * liA);
        Y[baseA + 32 + l31] = f2bf(o1a[r] * liA);
        size_t baseB = baseA + (size_t)32 * C_;
        Y[baseB + l31] = f2bf(o0b[r] * liB);
        Y[baseB + 32 + l31] = f2bf(o1b[r] * liB);
    }
}

// ---------------- K3: O projection + bias + residual, out (B,C,T) fp32 ----------------
__global__ __launch_bounds__(256) void k_oproj(const ushort* __restrict__ Y,
                                               const ushort* __restrict__ Wot,
                                               const float* __restrict__ bo,
                                               const float* __restrict__ x,
                                               float* __restrict__ out) {
    __shared__ __align__(16) ushort As[2][8192];
    __shared__ __align__(16) ushort Bs[2][8192];
    f32x4 acc[4][4];
    int tid = threadIdx.x;
    int L = blockIdx.x;
    int n = L >> 3, xcd = L & 7;
    int row0 = (xcd * 8 + (n & 7)) * 128;
    int col0 = (n >> 3) * 128;
    gemm_core(Y, Wot, row0, col0, tid, As, Bs, acc);
    int lane = tid & 63, w = tid >> 6;
    int wm = (w >> 1) * 64, wn = (w & 1) * 64;
#pragma unroll
    for (int mt = 0; mt < 4; mt++) {
        int grow0 = row0 + wm + mt * 16 + ((lane >> 4) << 2);
        int b = grow0 >> 10, t = grow0 & 1023;
#pragma unroll
        for (int nt = 0; nt < 4; nt++) {
            int c = col0 + wn + nt * 16 + (lane & 15);
            float bsv = bo[c];
            size_t off = ((size_t)b * C_ + c) * T_ + t;
            float4 xv = *(const float4*)(x + off);
            float4 ov;
            ov.x = acc[mt][nt][0] + xv.x + bsv;
            ov.y = acc[mt][nt][1] + xv.y + bsv;
            ov.z = acc[mt][nt][2] + xv.z + bsv;
            ov.w = acc[mt][nt][3] + xv.w + bsv;
            *(float4*)(out + off) = ov;
        }
    }
}

extern "C" void kernel_launch(void* const* d_in, const int* in_sizes, int n_in,
                              void* d_out, int out_size, void* d_ws, size_t ws_size,
                              hipStream_t stream) {
    const float* x  = (const float*)d_in[0];
    const float* Wq = (const float*)d_in[1];
    const float* bq = (const float*)d_in[2];
    const float* Wk = (const float*)d_in[3];
    const float* bk = (const float*)d_in[4];
    const float* Wv = (const float*)d_in[5];
    const float* bv = (const float*)d_in[6];
    const float* Wo = (const float*)d_in[7];
    const float* bo = (const float*)d_in[8];
    float* out = (float*)d_out;

    char* ws = (char*)d_ws;
    ushort* xt    = (ushort*)(ws + 0);          // 8 MB; reused as Y after K1
    ushort* Wqkvt = (ushort*)(ws + 8388608);
    ushort* Wot   = (ushort*)(ws + 9961472);
    ushort* Qh    = (ushort*)(ws + 10485760);
    ushort* Kh    = (ushort*)(ws + 18874368);
    ushort* Vt    = (ushort*)(ws + 27262976);
    ushort* Yw    = xt;

    k_prep<<<dim3(5120), 256, 0, stream>>>(x, Wq, Wk, Wv, Wo, xt, Wqkvt, Wot);
    k_qkv<<<dim3(768), 256, 0, stream>>>(xt, Wqkvt, bq, bk, bv, Qh, Kh, Vt);
    k_attn<<<dim3(256), 256, 0, stream>>>(Qh, Kh, Vt, Yw);
    k_oproj<<<dim3(256), 256, 0, stream>>>(Yw, Wot, bo, x, out);
}

// Round 15
// 75.561 us; speedup vs baseline: 3.4604x; 3.4604x over previous
//
#include <hip/hip_runtime.h>
#include <hip/hip_bf16.h>

#define B_  8
#define C_  512
#define T_  1024
#define NH_ 8
#define HD_ 64

// exp(S) computed as exp2(S*log2e); log2e folded into Wq/bq scale.
#define QSCALE 0.1803368801111243f   // 0.125 * log2(e)

using short8 = __attribute__((ext_vector_type(8))) short;
using f32x4  = __attribute__((ext_vector_type(4))) float;
using f32x16 = __attribute__((ext_vector_type(16))) float;
using us4    = __attribute__((ext_vector_type(4))) unsigned short;

__device__ __forceinline__ unsigned short f2bf(float f) {
    unsigned u = __builtin_bit_cast(unsigned, f);
    u += 0x7fff + ((u >> 16) & 1);
    return (unsigned short)(u >> 16);
}
__device__ __forceinline__ unsigned pack2bf(float lo, float hi) {
    __hip_bfloat162 h = __float22bfloat162_rn(float2{lo, hi});
    unsigned u;
    __builtin_memcpy(&u, &h, 4);
    return u;
}

// async global->LDS, 16B per lane. LDS dest = wave-uniform base + lane*16.
__device__ __forceinline__ void gload_lds16(const ushort* g, ushort* l) {
    __builtin_amdgcn_global_load_lds(
        (const __attribute__((address_space(1))) void*)g,
        (__attribute__((address_space(3))) void*)l, 16, 0, 0);
}

// counted vmcnt wait + scheduling fence (rule 18)
template <int N>
__device__ __forceinline__ void wait_vmcnt() {
    asm volatile("s_waitcnt vmcnt(%0)" ::"n"(N) : "memory");
    __builtin_amdgcn_sched_barrier(0);
}
__device__ __forceinline__ void barrier_raw() {
    __builtin_amdgcn_sched_barrier(0);
    __builtin_amdgcn_s_barrier();
}

// ---------------- K0: fused prep — x transpose + W transposes ----------------
__global__ __launch_bounds__(256) void k_prep(const float* __restrict__ x,
                                              const float* __restrict__ Wq,
                                              const float* __restrict__ Wk,
                                              const float* __restrict__ Wv,
                                              const float* __restrict__ Wo,
                                              ushort* __restrict__ xt,
                                              ushort* __restrict__ Wqkvt,
                                              ushort* __restrict__ Wot) {
    __shared__ float tile[32][33];
    int L = blockIdx.x;
    int tx = threadIdx.x & 31, ty = threadIdx.x >> 5;
    if (L < 4096) {
        int b = L >> 9, rem = L & 511;
        int t0 = (rem & 31) * 32, c0 = (rem >> 5) * 32;
#pragma unroll
        for (int i = 0; i < 4; i++)
            tile[ty + i * 8][tx] = x[((size_t)b * C_ + c0 + ty + i * 8) * T_ + t0 + tx];
        __syncthreads();
#pragma unroll
        for (int i = 0; i < 4; i++)
            xt[((size_t)b * T_ + t0 + ty + i * 8) * C_ + c0 + tx] = f2bf(tile[tx][ty + i * 8]);
    } else {
        int LL = L - 4096;
        int m = LL >> 8, rem = LL & 255;
        int k0 = (rem & 15) * 32, n0 = (rem >> 4) * 32;
        const float* W = (m == 0) ? Wq : (m == 1) ? Wk : (m == 2) ? Wv : Wo;
        ushort* dst = (m < 3) ? (Wqkvt + (size_t)m * C_ * C_) : Wot;
        float scale = (m == 0) ? QSCALE : 1.0f;
#pragma unroll
        for (int i = 0; i < 4; i++)
            tile[ty + i * 8][tx] = W[(size_t)(k0 + ty + i * 8) * C_ + n0 + tx];
        __syncthreads();
#pragma unroll
        for (int i = 0; i < 4; i++)
            dst[(size_t)(n0 + ty + i * 8) * C_ + k0 + tx] = f2bf(tile[tx][ty + i * 8] * scale);
    }
}

// ---------------- GEMM mainloop: C[128x128] = A[128xK] * Bt[128xK]^T ----------------
__device__ __forceinline__ void gemm_core(const ushort* __restrict__ A,
                                          const ushort* __restrict__ Bt,
                                          int row0, int col0, int tid,
                                          ushort (*As)[8192], ushort (*Bs)[8192],
                                          f32x4 acc[4][4]) {
    f32x4 zero = {0.f, 0.f, 0.f, 0.f};
#pragma unroll
    for (int i = 0; i < 4; i++)
#pragma unroll
        for (int j = 0; j < 4; j++) acc[i][j] = zero;
    int lane = tid & 63, w = tid >> 6;
    int ql = lane & 15, g = lane >> 4;
    int wm = (w >> 1) * 64, wn = (w & 1) * 64;
    int srow = lane >> 3;
    int scol8 = (lane & 7) ^ (srow & 7);

#pragma unroll
    for (int i = 0; i < 4; i++) {
        int c = w * 4 + i;
        int r = c * 8 + srow;
        gload_lds16(A + (size_t)(row0 + r) * C_ + scol8 * 8, As[0] + c * 512);
        gload_lds16(Bt + (size_t)(col0 + r) * C_ + scol8 * 8, Bs[0] + c * 512);
    }

#pragma unroll
    for (int kt = 0; kt < 8; kt++) {
        int cur = kt & 1;
        if (kt < 7) {
            int k0 = (kt + 1) * 64;
#pragma unroll
            for (int i = 0; i < 4; i++) {
                int c = w * 4 + i;
                int r = c * 8 + srow;
                gload_lds16(A + (size_t)(row0 + r) * C_ + k0 + scol8 * 8, As[cur ^ 1] + c * 512);
                gload_lds16(Bt + (size_t)(col0 + r) * C_ + k0 + scol8 * 8, Bs[cur ^ 1] + c * 512);
            }
            wait_vmcnt<8>();
        } else {
            wait_vmcnt<0>();
        }
        barrier_raw();
        const ushort* Ac = As[cur];
        const ushort* Bc = Bs[cur];
        __builtin_amdgcn_s_setprio(1);
#pragma unroll
        for (int s = 0; s < 2; s++) {
            short8 a[4], b[4];
            int cs = ((4 * s + g) ^ (ql & 7)) * 8;
#pragma unroll
            for (int mt = 0; mt < 4; mt++)
                a[mt] = *(const short8*)(Ac + (wm + mt * 16 + ql) * 64 + cs);
#pragma unroll
            for (int nt = 0; nt < 4; nt++)
                b[nt] = *(const short8*)(Bc + (wn + nt * 16 + ql) * 64 + cs);
#pragma unroll
            for (int mt = 0; mt < 4; mt++)
#pragma unroll
                for (int nt = 0; nt < 4; nt++)
                    acc[mt][nt] = __builtin_amdgcn_mfma_f32_16x16x32_bf16(
                        a[mt], b[nt], acc[mt][nt], 0, 0, 0);
        }
        __builtin_amdgcn_s_setprio(0);
        barrier_raw();
    }
}

// ---------------- K1: QKV projection, LDS-bounce epilogue ----------------
__global__ __launch_bounds__(256) void k_qkv(const ushort* __restrict__ xt,
                                             const ushort* __restrict__ Wqkvt,
                                             const float* __restrict__ bq,
                                             const float* __restrict__ bk,
                                             const float* __restrict__ bv,
                                             ushort* __restrict__ Qh,
                                             ushort* __restrict__ Kh,
                                             ushort* __restrict__ Vt) {
    __shared__ __align__(16) ushort As[2][8192];
    __shared__ __align__(16) ushort Bs[2][8192];
    f32x4 acc[4][4];
    int tid = threadIdx.x;
    int L = blockIdx.x;
    int n = L >> 3, xcd = L & 7;
    int row0 = (xcd * 8 + (n & 7)) * 128;
    int col0 = (n >> 3) * 128;
    gemm_core(xt, Wqkvt, row0, col0, tid, As, Bs, acc);
    int lane = tid & 63, w = tid >> 6;
    int ql = lane & 15, g = lane >> 4;
    int wm = (w >> 1) * 64, wn = (w & 1) * 64;
    int which = col0 >> 9;  // 0=Q 1=K 2=V
    const float* bias = (which == 0) ? bq : (which == 1) ? bk : bv;
    float bscale = (which == 0) ? QSCALE : 1.0f;
    ushort* Lt = &As[0][0];  // 32KB bounce tile (gemm LDS dead)

    if (which != 2) {
        ushort* dst = (which == 0) ? Qh : Kh;
#pragma unroll
        for (int mt = 0; mt < 4; mt++)
#pragma unroll
            for (int nt = 0; nt < 4; nt++) {
                int col = wn + nt * 16 + ql;
                float bsv = bias[(col0 + col) & 511] * bscale;
#pragma unroll
                for (int r = 0; r < 4; r++) {
                    int row = wm + mt * 16 + 4 * g + r;
                    int sw = col ^ ((row & 7) << 3);
                    Lt[row * 128 + sw] = f2bf(acc[mt][nt][r] + bsv);
                }
            }
        __syncthreads();
#pragma unroll
        for (int i = 0; i < 8; i++) {
            int task = w * 512 + i * 64 + lane;
            int row = task >> 4, gran = task & 15;
            int sg = gran ^ (row & 7);
            short8 vle = *(const short8*)(Lt + row * 128 + sg * 8);
            int gcol = col0 + gran * 8;
            int hc = gcol & 511, h = hc >> 6, d = hc & 63;
            int grow = row0 + row, b = grow >> 10, t = grow & 1023;
            *(short8*)(dst + ((size_t)(b * NH_ + h) * T_ + t) * HD_ + d) = vle;
        }
    } else {
#pragma unroll
        for (int mt = 0; mt < 4; mt++)
#pragma unroll
            for (int nt = 0; nt < 4; nt++) {
                int col = wn + nt * 16 + ql;
                float bsv = bias[(col0 + col) & 511] * bscale;
                int rowb = wm + mt * 16 + 4 * g;
                int swz = (rowb >> 2) ^ (col & 31);
                us4 pk;
#pragma unroll
                for (int r = 0; r < 4; r++) pk[r] = f2bf(acc[mt][nt][r] + bsv);
                *(us4*)(Lt + col * 128 + swz * 4) = pk;
            }
        __syncthreads();
#pragma unroll
        for (int i = 0; i < 8; i++) {
            int task = w * 512 + i * 64 + lane;
            int colr = task >> 4, gran = task & 15;
            int g4a = (2 * gran) ^ (colr & 31);
            int g4b = (2 * gran + 1) ^ (colr & 31);
            us4 lo = *(const us4*)(Lt + colr * 128 + g4a * 4);
            us4 hi4 = *(const us4*)(Lt + colr * 128 + g4b * 4);
            us4 arr[2] = {lo, hi4};
            short8 vle;
            __builtin_memcpy(&vle, arr, 16);
            int gcol = col0 + colr;
            int hc = gcol & 511, h = hc >> 6, d = hc & 63;
            int grow = row0 + gran * 8, b = grow >> 10, t = grow & 1023;
            *(short8*)(Vt + ((size_t)(b * NH_ + h) * HD_ + d) * T_ + t) = vle;
        }
    }
}

// ---------------- K2: flash attention, 64 q-rows/wave ----------------
// QBLK=256, 4 waves x 64 q-rows, grid 256 (1 block/CU).
// __launch_bounds__(256, 1): 1 wave/EU -> 512-VGPR budget, NO SPILL (R14 bug).
// Each K/V fragment read once per wave feeds TWO q-halves -> LDS bytes/q halved.
__global__ __launch_bounds__(256, 1) void k_attn(const ushort* __restrict__ Qh,
                                                 const ushort* __restrict__ Kh,
                                                 const ushort* __restrict__ Vt,
                                                 ushort* __restrict__ Y) {
    __shared__ __align__(16) ushort KV[8][4096];  // K slots 0-3, V slots 4-7
    int tid = threadIdx.x, lane = tid & 63, w = tid >> 6;
    int hi = lane >> 5, l31 = lane & 31, l7 = lane & 7;
    int bh = blockIdx.x & 63, q0 = (blockIdx.x >> 6) * 256;
    int b = bh >> 3, h = bh & 7;
    int srow = lane >> 3;
    int scol8 = l7 ^ (srow & 7);
    const ushort* Kbase = Kh + (size_t)bh * T_ * HD_;
    const ushort* Vbase = Vt + (size_t)bh * HD_ * T_;
    const ushort* kv = &KV[0][0];

    // two q-halves per wave: rows q0 + w*64 + [0,32) and [32,64)
    short8 qaA[4], qaB[4];
#pragma unroll
    for (int s = 0; s < 4; s++) {
        size_t rbase = (size_t)bh * T_ + q0 + w * 64 + l31;
        qaA[s] = *(const short8*)(Qh + rbase * HD_ + s * 16 + hi * 8);
        qaB[s] = *(const short8*)(Qh + (rbase + 32) * HD_ + s * 16 + hi * 8);
    }

    int fofs[4];
#pragma unroll
    for (int s = 0; s < 4; s++) fofs[s] = ((2 * s + hi) ^ l7) * 8;
    int rowlo = l31 * 64;

    short8 ones;
    {
        short ov = (l31 == 0) ? (short)0x3F80 : (short)0;
#pragma unroll
        for (int j = 0; j < 8; j++) ones[j] = ov;
    }

    f32x16 o0a, o1a, o0b, o1b, o5a, o5b, z16;
#pragma unroll
    for (int i = 0; i < 16; i++) {
        o0a[i] = 0.f; o1a[i] = 0.f; o0b[i] = 0.f; o1b[i] = 0.f;
        o5a[i] = 0.f; o5b[i] = 0.f; z16[i] = 0.f;
    }

    // prologue: tiles 0,1 -> slots 0,1
#pragma unroll
    for (int tt = 0; tt < 2; tt++) {
#pragma unroll
        for (int i = 0; i < 2; i++) {
            int c = w * 2 + i;
            int r = c * 8 + srow;
            gload_lds16(Kbase + (size_t)(tt * 64 + r) * HD_ + scol8 * 8,
                        &KV[tt][0] + c * 512);
            gload_lds16(Vbase + (size_t)r * T_ + tt * 64 + scol8 * 8,
                        &KV[4 + tt][0] + c * 512);
        }
    }

#pragma unroll
    for (int t = 0; t < 16; t++) {
        const int sl = t & 3;
        if (t < 14) {
            const int ds = (t + 2) & 3;
            int kv0 = (t + 2) * 64;
#pragma unroll
            for (int i = 0; i < 2; i++) {
                int c = w * 2 + i;
                int r = c * 8 + srow;
                gload_lds16(Kbase + (size_t)(kv0 + r) * HD_ + scol8 * 8,
                            &KV[ds][0] + c * 512);
                gload_lds16(Vbase + (size_t)r * T_ + kv0 + scol8 * 8,
                            &KV[4 + ds][0] + c * 512);
            }
            wait_vmcnt<8>();
        } else if (t == 14) {
            wait_vmcnt<4>();
        } else {
            wait_vmcnt<0>();
        }
        barrier_raw();

        // S^T[k][q]: each ka pair feeds both q-halves
        f32x16 sTa0, sTa1, sTb0, sTb1;
        __builtin_amdgcn_s_setprio(1);
        {
            short8 ka0 = *(const short8*)(kv + sl * 4096 + rowlo + fofs[0]);
            short8 ka1 = *(const short8*)(kv + sl * 4096 + 2048 + rowlo + fofs[0]);
            sTa0 = __builtin_amdgcn_mfma_f32_32x32x16_bf16(ka0, qaA[0], z16, 0, 0, 0);
            sTa1 = __builtin_amdgcn_mfma_f32_32x32x16_bf16(ka1, qaA[0], z16, 0, 0, 0);
            sTb0 = __builtin_amdgcn_mfma_f32_32x32x16_bf16(ka0, qaB[0], z16, 0, 0, 0);
            sTb1 = __builtin_amdgcn_mfma_f32_32x32x16_bf16(ka1, qaB[0], z16, 0, 0, 0);
        }
#pragma unroll
        for (int s = 1; s < 4; s++) {
            short8 ka0 = *(const short8*)(kv + sl * 4096 + rowlo + fofs[s]);
            short8 ka1 = *(const short8*)(kv + sl * 4096 + 2048 + rowlo + fofs[s]);
            sTa0 = __builtin_amdgcn_mfma_f32_32x32x16_bf16(ka0, qaA[s], sTa0, 0, 0, 0);
            sTa1 = __builtin_amdgcn_mfma_f32_32x32x16_bf16(ka1, qaA[s], sTa1, 0, 0, 0);
            sTb0 = __builtin_amdgcn_mfma_f32_32x32x16_bf16(ka0, qaB[s], sTb0, 0, 0, 0);
            sTb1 = __builtin_amdgcn_mfma_f32_32x32x16_bf16(ka1, qaB[s], sTb1, 0, 0, 0);
        }
        __builtin_amdgcn_s_setprio(0);

        // P = exp2(S), pack bf16 pairs
        unsigned pkva0[8], pkva1[8], pkvb0[8], pkvb1[8];
#pragma unroll
        for (int i = 0; i < 8; i++) {
            pkva0[i] = pack2bf(__builtin_amdgcn_exp2f(sTa0[2 * i]),
                               __builtin_amdgcn_exp2f(sTa0[2 * i + 1]));
            pkva1[i] = pack2bf(__builtin_amdgcn_exp2f(sTa1[2 * i]),
                               __builtin_amdgcn_exp2f(sTa1[2 * i + 1]));
            pkvb0[i] = pack2bf(__builtin_amdgcn_exp2f(sTb0[2 * i]),
                               __builtin_amdgcn_exp2f(sTb0[2 * i + 1]));
            pkvb1[i] = pack2bf(__builtin_amdgcn_exp2f(sTb1[2 * i]),
                               __builtin_amdgcn_exp2f(sTb1[2 * i + 1]));
        }

        // PV + ones-lsum: each vb pair feeds both q-halves
        __builtin_amdgcn_s_setprio(1);
#pragma unroll
        for (int t4 = 0; t4 < 4; t4++) {
            const int h2 = t4 & 1;
            unsigned a0, a1, a2, a3, b0, b1, b2, b3;
            if (t4 < 2) {
                a0 = pkva0[4 * h2 + 0]; a2 = pkva0[4 * h2 + 2];
                a1 = pkva0[4 * h2 + 1]; a3 = pkva0[4 * h2 + 3];
                b0 = pkvb0[4 * h2 + 0]; b2 = pkvb0[4 * h2 + 2];
                b1 = pkvb0[4 * h2 + 1]; b3 = pkvb0[4 * h2 + 3];
            } else {
                a0 = pkva1[4 * h2 + 0]; a2 = pkva1[4 * h2 + 2];
                a1 = pkva1[4 * h2 + 1]; a3 = pkva1[4 * h2 + 3];
                b0 = pkvb1[4 * h2 + 0]; b2 = pkvb1[4 * h2 + 2];
                b1 = pkvb1[4 * h2 + 1]; b3 = pkvb1[4 * h2 + 3];
            }
            asm("v_permlane32_swap_b32 %0, %1" : "+v"(a0), "+v"(a2));
            asm("v_permlane32_swap_b32 %0, %1" : "+v"(a1), "+v"(a3));
            asm("v_permlane32_swap_b32 %0, %1" : "+v"(b0), "+v"(b2));
            asm("v_permlane32_swap_b32 %0, %1" : "+v"(b1), "+v"(b3));
            unsigned auA[4] = {a0, a1, a2, a3};
            unsigned auB[4] = {b0, b1, b2, b3};
            short8 paA, paB;
            __builtin_memcpy(&paA, auA, 16);
            __builtin_memcpy(&paB, auB, 16);
            short8 vb0 = *(const short8*)(kv + (4 + sl) * 4096 + rowlo + fofs[t4]);
            short8 vb1 = *(const short8*)(kv + (4 + sl) * 4096 + 2048 + rowlo + fofs[t4]);
            o0a = __builtin_amdgcn_mfma_f32_32x32x16_bf16(paA, vb0, o0a, 0, 0, 0);
            o1a = __builtin_amdgcn_mfma_f32_32x32x16_bf16(paA, vb1, o1a, 0, 0, 0);
            o0b = __builtin_amdgcn_mfma_f32_32x32x16_bf16(paB, vb0, o0b, 0, 0, 0);
            o1b = __builtin_amdgcn_mfma_f32_32x32x16_bf16(paB, vb1, o1b, 0, 0, 0);
            o5a = __builtin_amdgcn_mfma_f32_32x32x16_bf16(paA, ones, o5a, 0, 0, 0);
            o5b = __builtin_amdgcn_mfma_f32_32x32x16_bf16(paB, ones, o5b, 0, 0, 0);
        }
        __builtin_amdgcn_s_setprio(0);
        // no second barrier: slot reuse distance (4) > prefetch depth (2)
    }

#pragma unroll
    for (int r = 0; r < 16; r++) {
        int qr = (r & 3) + 8 * (r >> 2) + 4 * hi;
        float liA = 1.0f / __shfl(o5a[r], hi * 32);
        float liB = 1.0f / __shfl(o5b[r], hi * 32);
        int trowA = q0 + w * 64 + qr;
        size_t baseA = ((size_t)b * T_ + trowA) * C_ + h * HD_;
        Y[baseA + l31] = f2bf(o0a[r] * liA);
        Y[baseA + 32 + l31] = f2bf(o1a[r] * liA);
        size_t baseB = baseA + (size_t)32 * C_;
        Y[baseB + l31] = f2bf(o0b[r] * liB);
        Y[baseB + 32 + l31] = f2bf(o1b[r] * liB);
    }
}

// ---------------- K3: O projection + bias + residual, out (B,C,T) fp32 ----------------
__global__ __launch_bounds__(256) void k_oproj(const ushort* __restrict__ Y,
                                               const ushort* __restrict__ Wot,
                                               const float* __restrict__ bo,
                                               const float* __restrict__ x,
                                               float* __restrict__ out) {
    __shared__ __align__(16) ushort As[2][8192];
    __shared__ __align__(16) ushort Bs[2][8192];
    f32x4 acc[4][4];
    int tid = threadIdx.x;
    int L = blockIdx.x;
    int n = L >> 3, xcd = L & 7;
    int row0 = (xcd * 8 + (n & 7)) * 128;
    int col0 = (n >> 3) * 128;
    gemm_core(Y, Wot, row0, col0, tid, As, Bs, acc);
    int lane = tid & 63, w = tid >> 6;
    int wm = (w >> 1) * 64, wn = (w & 1) * 64;
#pragma unroll
    for (int mt = 0; mt < 4; mt++) {
        int grow0 = row0 + wm + mt * 16 + ((lane >> 4) << 2);
        int b = grow0 >> 10, t = grow0 & 1023;
#pragma unroll
        for (int nt = 0; nt < 4; nt++) {
            int c = col0 + wn + nt * 16 + (lane & 15);
            float bsv = bo[c];
            size_t off = ((size_t)b * C_ + c) * T_ + t;
            float4 xv = *(const float4*)(x + off);
            float4 ov;
            ov.x = acc[mt][nt][0] + xv.x + bsv;
            ov.y = acc[mt][nt][1] + xv.y + bsv;
            ov.z = acc[mt][nt][2] + xv.z + bsv;
            ov.w = acc[mt][nt][3] + xv.w + bsv;
            *(float4*)(out + off) = ov;
        }
    }
}

extern "C" void kernel_launch(void* const* d_in, const int* in_sizes, int n_in,
                              void* d_out, int out_size, void* d_ws, size_t ws_size,
                              hipStream_t stream) {
    const float* x  = (const float*)d_in[0];
    const float* Wq = (const float*)d_in[1];
    const float* bq = (const float*)d_in[2];
    const float* Wk = (const float*)d_in[3];
    const float* bk = (const float*)d_in[4];
    const float* Wv = (const float*)d_in[5];
    const float* bv = (const float*)d_in[6];
    const float* Wo = (const float*)d_in[7];
    const float* bo = (const float*)d_in[8];
    float* out = (float*)d_out;

    char* ws = (char*)d_ws;
    ushort* xt    = (ushort*)(ws + 0);          // 8 MB; reused as Y after K1
    ushort* Wqkvt = (ushort*)(ws + 8388608);
    ushort* Wot   = (ushort*)(ws + 9961472);
    ushort* Qh    = (ushort*)(ws + 10485760);
    ushort* Kh    = (ushort*)(ws + 18874368);
    ushort* Vt    = (ushort*)(ws + 27262976);
    ushort* Yw    = xt;

    k_prep<<<dim3(5120), 256, 0, stream>>>(x, Wq, Wk, Wv, Wo, xt, Wqkvt, Wot);
    k_qkv<<<dim3(768), 256, 0, stream>>>(xt, Wqkvt, bq, bk, bv, Qh, Kh, Vt);
    k_attn<<<dim3(256), 256, 0, stream>>>(Qh, Kh, Vt, Yw);
    k_oproj<<<dim3(256), 256, 0, stream>>>(Yw, Wot, bo, x, out);
}

// Round 16
// 72.408 us; speedup vs baseline: 3.6111x; 1.0435x over previous
//
#include <hip/hip_runtime.h>
#include <hip/hip_bf16.h>

#define B_  8
#define C_  512
#define T_  1024
#define NH_ 8
#define HD_ 64

// exp(S) computed as exp2(S*log2e); log2e folded into Wq/bq scale.
#define QSCALE 0.1803368801111243f   // 0.125 * log2(e)

using short8 = __attribute__((ext_vector_type(8))) short;
using f32x4  = __attribute__((ext_vector_type(4))) float;
using f32x16 = __attribute__((ext_vector_type(16))) float;
using us4    = __attribute__((ext_vector_type(4))) unsigned short;

__device__ __forceinline__ unsigned short f2bf(float f) {
    unsigned u = __builtin_bit_cast(unsigned, f);
    u += 0x7fff + ((u >> 16) & 1);
    return (unsigned short)(u >> 16);
}
__device__ __forceinline__ unsigned pack2bf(float lo, float hi) {
    __hip_bfloat162 h = __float22bfloat162_rn(float2{lo, hi});
    unsigned u;
    __builtin_memcpy(&u, &h, 4);
    return u;
}

// async global->LDS, 16B per lane. LDS dest = wave-uniform base + lane*16.
__device__ __forceinline__ void gload_lds16(const ushort* g, ushort* l) {
    __builtin_amdgcn_global_load_lds(
        (const __attribute__((address_space(1))) void*)g,
        (__attribute__((address_space(3))) void*)l, 16, 0, 0);
}

// counted vmcnt wait + scheduling fence (rule 18)
template <int N>
__device__ __forceinline__ void wait_vmcnt() {
    asm volatile("s_waitcnt vmcnt(%0)" ::"n"(N) : "memory");
    __builtin_amdgcn_sched_barrier(0);
}
__device__ __forceinline__ void barrier_raw() {
    __builtin_amdgcn_sched_barrier(0);
    __builtin_amdgcn_s_barrier();
}

// ---------------- K0: fused prep — x transpose + W transposes ----------------
__global__ __launch_bounds__(256) void k_prep(const float* __restrict__ x,
                                              const float* __restrict__ Wq,
                                              const float* __restrict__ Wk,
                                              const float* __restrict__ Wv,
                                              const float* __restrict__ Wo,
                                              ushort* __restrict__ xt,
                                              ushort* __restrict__ Wqkvt,
                                              ushort* __restrict__ Wot) {
    __shared__ float tile[32][33];
    int L = blockIdx.x;
    int tx = threadIdx.x & 31, ty = threadIdx.x >> 5;
    if (L < 4096) {
        int b = L >> 9, rem = L & 511;
        int t0 = (rem & 31) * 32, c0 = (rem >> 5) * 32;
#pragma unroll
        for (int i = 0; i < 4; i++)
            tile[ty + i * 8][tx] = x[((size_t)b * C_ + c0 + ty + i * 8) * T_ + t0 + tx];
        __syncthreads();
#pragma unroll
        for (int i = 0; i < 4; i++)
            xt[((size_t)b * T_ + t0 + ty + i * 8) * C_ + c0 + tx] = f2bf(tile[tx][ty + i * 8]);
    } else {
        int LL = L - 4096;
        int m = LL >> 8, rem = LL & 255;
        int k0 = (rem & 15) * 32, n0 = (rem >> 4) * 32;
        const float* W = (m == 0) ? Wq : (m == 1) ? Wk : (m == 2) ? Wv : Wo;
        ushort* dst = (m < 3) ? (Wqkvt + (size_t)m * C_ * C_) : Wot;
        float scale = (m == 0) ? QSCALE : 1.0f;
#pragma unroll
        for (int i = 0; i < 4; i++)
            tile[ty + i * 8][tx] = W[(size_t)(k0 + ty + i * 8) * C_ + n0 + tx];
        __syncthreads();
#pragma unroll
        for (int i = 0; i < 4; i++)
            dst[(size_t)(n0 + ty + i * 8) * C_ + k0 + tx] = f2bf(tile[tx][ty + i * 8] * scale);
    }
}

// ---------------- GEMM mainloop: C[128x128] = A[128xK] * Bt[128xK]^T ----------------
__device__ __forceinline__ void gemm_core(const ushort* __restrict__ A,
                                          const ushort* __restrict__ Bt,
                                          int row0, int col0, int tid,
                                          ushort (*As)[8192], ushort (*Bs)[8192],
                                          f32x4 acc[4][4]) {
    f32x4 zero = {0.f, 0.f, 0.f, 0.f};
#pragma unroll
    for (int i = 0; i < 4; i++)
#pragma unroll
        for (int j = 0; j < 4; j++) acc[i][j] = zero;
    int lane = tid & 63, w = tid >> 6;
    int ql = lane & 15, g = lane >> 4;
    int wm = (w >> 1) * 64, wn = (w & 1) * 64;
    int srow = lane >> 3;
    int scol8 = (lane & 7) ^ (srow & 7);

#pragma unroll
    for (int i = 0; i < 4; i++) {
        int c = w * 4 + i;
        int r = c * 8 + srow;
        gload_lds16(A + (size_t)(row0 + r) * C_ + scol8 * 8, As[0] + c * 512);
        gload_lds16(Bt + (size_t)(col0 + r) * C_ + scol8 * 8, Bs[0] + c * 512);
    }

#pragma unroll
    for (int kt = 0; kt < 8; kt++) {
        int cur = kt & 1;
        if (kt < 7) {
            int k0 = (kt + 1) * 64;
#pragma unroll
            for (int i = 0; i < 4; i++) {
                int c = w * 4 + i;
                int r = c * 8 + srow;
                gload_lds16(A + (size_t)(row0 + r) * C_ + k0 + scol8 * 8, As[cur ^ 1] + c * 512);
                gload_lds16(Bt + (size_t)(col0 + r) * C_ + k0 + scol8 * 8, Bs[cur ^ 1] + c * 512);
            }
            wait_vmcnt<8>();
        } else {
            wait_vmcnt<0>();
        }
        barrier_raw();
        const ushort* Ac = As[cur];
        const ushort* Bc = Bs[cur];
        __builtin_amdgcn_s_setprio(1);
#pragma unroll
        for (int s = 0; s < 2; s++) {
            short8 a[4], b[4];
            int cs = ((4 * s + g) ^ (ql & 7)) * 8;
#pragma unroll
            for (int mt = 0; mt < 4; mt++)
                a[mt] = *(const short8*)(Ac + (wm + mt * 16 + ql) * 64 + cs);
#pragma unroll
            for (int nt = 0; nt < 4; nt++)
                b[nt] = *(const short8*)(Bc + (wn + nt * 16 + ql) * 64 + cs);
#pragma unroll
            for (int mt = 0; mt < 4; mt++)
#pragma unroll
                for (int nt = 0; nt < 4; nt++)
                    acc[mt][nt] = __builtin_amdgcn_mfma_f32_16x16x32_bf16(
                        a[mt], b[nt], acc[mt][nt], 0, 0, 0);
        }
        __builtin_amdgcn_s_setprio(0);
        barrier_raw();
    }
}

// ---------------- K1: QKV projection, LDS-bounce epilogue ----------------
__global__ __launch_bounds__(256) void k_qkv(const ushort* __restrict__ xt,
                                             const ushort* __restrict__ Wqkvt,
                                             const float* __restrict__ bq,
                                             const float* __restrict__ bk,
                                             const float* __restrict__ bv,
                                             ushort* __restrict__ Qh,
                                             ushort* __restrict__ Kh,
                                             ushort* __restrict__ Vt) {
    __shared__ __align__(16) ushort As[2][8192];
    __shared__ __align__(16) ushort Bs[2][8192];
    f32x4 acc[4][4];
    int tid = threadIdx.x;
    int L = blockIdx.x;
    int n = L >> 3, xcd = L & 7;
    int row0 = (xcd * 8 + (n & 7)) * 128;
    int col0 = (n >> 3) * 128;
    gemm_core(xt, Wqkvt, row0, col0, tid, As, Bs, acc);
    int lane = tid & 63, w = tid >> 6;
    int ql = lane & 15, g = lane >> 4;
    int wm = (w >> 1) * 64, wn = (w & 1) * 64;
    int which = col0 >> 9;  // 0=Q 1=K 2=V
    const float* bias = (which == 0) ? bq : (which == 1) ? bk : bv;
    float bscale = (which == 0) ? QSCALE : 1.0f;
    ushort* Lt = &As[0][0];  // 32KB bounce tile (gemm LDS dead)

    if (which != 2) {
        ushort* dst = (which == 0) ? Qh : Kh;
#pragma unroll
        for (int mt = 0; mt < 4; mt++)
#pragma unroll
            for (int nt = 0; nt < 4; nt++) {
                int col = wn + nt * 16 + ql;
                float bsv = bias[(col0 + col) & 511] * bscale;
#pragma unroll
                for (int r = 0; r < 4; r++) {
                    int row = wm + mt * 16 + 4 * g + r;
                    int sw = col ^ ((row & 7) << 3);
                    Lt[row * 128 + sw] = f2bf(acc[mt][nt][r] + bsv);
                }
            }
        __syncthreads();
#pragma unroll
        for (int i = 0; i < 8; i++) {
            int task = w * 512 + i * 64 + lane;
            int row = task >> 4, gran = task & 15;
            int sg = gran ^ (row & 7);
            short8 vle = *(const short8*)(Lt + row * 128 + sg * 8);
            int gcol = col0 + gran * 8;
            int hc = gcol & 511, h = hc >> 6, d = hc & 63;
            int grow = row0 + row, b = grow >> 10, t = grow & 1023;
            *(short8*)(dst + ((size_t)(b * NH_ + h) * T_ + t) * HD_ + d) = vle;
        }
    } else {
#pragma unroll
        for (int mt = 0; mt < 4; mt++)
#pragma unroll
            for (int nt = 0; nt < 4; nt++) {
                int col = wn + nt * 16 + ql;
                float bsv = bias[(col0 + col) & 511] * bscale;
                int rowb = wm + mt * 16 + 4 * g;
                int swz = (rowb >> 2) ^ (col & 31);
                us4 pk;
#pragma unroll
                for (int r = 0; r < 4; r++) pk[r] = f2bf(acc[mt][nt][r] + bsv);
                *(us4*)(Lt + col * 128 + swz * 4) = pk;
            }
        __syncthreads();
#pragma unroll
        for (int i = 0; i < 8; i++) {
            int task = w * 512 + i * 64 + lane;
            int colr = task >> 4, gran = task & 15;
            int g4a = (2 * gran) ^ (colr & 31);
            int g4b = (2 * gran + 1) ^ (colr & 31);
            us4 lo = *(const us4*)(Lt + colr * 128 + g4a * 4);
            us4 hi4 = *(const us4*)(Lt + colr * 128 + g4b * 4);
            us4 arr[2] = {lo, hi4};
            short8 vle;
            __builtin_memcpy(&vle, arr, 16);
            int gcol = col0 + colr;
            int hc = gcol & 511, h = hc >> 6, d = hc & 63;
            int grow = row0 + gran * 8, b = grow >> 10, t = grow & 1023;
            *(short8*)(Vt + ((size_t)(b * NH_ + h) * HD_ + d) * T_ + t) = vle;
        }
    }
}

// ---------------- K2: flash attention, 32x32 MFMA, in-register P ----------------
// R13 base (QBLK=128, 4 waves, 4-slot pipeline, single barrier) +
// T15 double-pipeline: PV(t-1) issued right after QK(t) so its MFMAs overlap
// exp/pack(t) VALU/trans work. Prefetch moved AFTER the barrier (V-slot read
// distance is now t-1; pre-barrier prefetch of t+2 would clobber slot (t-2)&3).
__global__ __launch_bounds__(256) void k_attn(const ushort* __restrict__ Qh,
                                              const ushort* __restrict__ Kh,
                                              const ushort* __restrict__ Vt,
                                              ushort* __restrict__ Y) {
    __shared__ __align__(16) ushort KV[8][4096];  // K slots 0-3, V slots 4-7
    int tid = threadIdx.x, lane = tid & 63, w = tid >> 6;
    int hi = lane >> 5, l31 = lane & 31, l7 = lane & 7;
    int bh = blockIdx.x & 63, q0 = (blockIdx.x >> 6) * 128;
    int b = bh >> 3, h = bh & 7;
    int srow = lane >> 3;
    int scol8 = l7 ^ (srow & 7);
    const ushort* Kbase = Kh + (size_t)bh * T_ * HD_;
    const ushort* Vbase = Vt + (size_t)bh * HD_ * T_;
    const ushort* kv = &KV[0][0];

    short8 qa[4];
#pragma unroll
    for (int s = 0; s < 4; s++)
        qa[s] = *(const short8*)(Qh + ((size_t)bh * T_ + q0 + w * 32 + l31) * HD_ +
                                 s * 16 + hi * 8);

    int fofs[4];
#pragma unroll
    for (int s = 0; s < 4; s++) fofs[s] = ((2 * s + hi) ^ l7) * 8;
    int rowlo = l31 * 64;

    short8 ones;
    {
        short ov = (l31 == 0) ? (short)0x3F80 : (short)0;
#pragma unroll
        for (int j = 0; j < 8; j++) ones[j] = ov;
    }

    f32x16 o0, o1, o5, z16;
#pragma unroll
    for (int i = 0; i < 16; i++) { o0[i] = 0.f; o1[i] = 0.f; o5[i] = 0.f; z16[i] = 0.f; }

    // parity-banked packed-P from previous tile (compile-time indexed)
    unsigned pk0[2][8], pk1[2][8];

// PV of tile with packed-P banks P0/P1 against V slot VSL (+ ones-lsum)
#define PV_BLOCK(P0, P1, VSL)                                                   \
    __builtin_amdgcn_s_setprio(1);                                              \
    _Pragma("unroll")                                                           \
    for (int t4 = 0; t4 < 4; t4++) {                                            \
        const int h2 = t4 & 1;                                                  \
        unsigned c0, c1, c2v, c3v;                                              \
        if (t4 < 2) { c0 = (P0)[4 * h2 + 0]; c2v = (P0)[4 * h2 + 2];            \
                      c1 = (P0)[4 * h2 + 1]; c3v = (P0)[4 * h2 + 3]; }          \
        else        { c0 = (P1)[4 * h2 + 0]; c2v = (P1)[4 * h2 + 2];            \
                      c1 = (P1)[4 * h2 + 1]; c3v = (P1)[4 * h2 + 3]; }          \
        asm("v_permlane32_swap_b32 %0, %1" : "+v"(c0), "+v"(c2v));              \
        asm("v_permlane32_swap_b32 %0, %1" : "+v"(c1), "+v"(c3v));              \
        unsigned au[4] = {c0, c1, c2v, c3v};                                    \
        short8 pa;                                                              \
        __builtin_memcpy(&pa, au, 16);                                          \
        short8 vb0 = *(const short8*)(kv + (4 + (VSL)) * 4096 + rowlo + fofs[t4]);        \
        short8 vb1 = *(const short8*)(kv + (4 + (VSL)) * 4096 + 2048 + rowlo + fofs[t4]); \
        o0 = __builtin_amdgcn_mfma_f32_32x32x16_bf16(pa, vb0, o0, 0, 0, 0);     \
        o1 = __builtin_amdgcn_mfma_f32_32x32x16_bf16(pa, vb1, o1, 0, 0, 0);     \
        o5 = __builtin_amdgcn_mfma_f32_32x32x16_bf16(pa, ones, o5, 0, 0, 0);    \
    }                                                                           \
    __builtin_amdgcn_s_setprio(0);

    // prologue: tiles 0,1 -> slots 0,1
#pragma unroll
    for (int tt = 0; tt < 2; tt++) {
#pragma unroll
        for (int i = 0; i < 2; i++) {
            int c = w * 2 + i;
            int r = c * 8 + srow;
            gload_lds16(Kbase + (size_t)(tt * 64 + r) * HD_ + scol8 * 8,
                        &KV[tt][0] + c * 512);
            gload_lds16(Vbase + (size_t)r * T_ + tt * 64 + scol8 * 8,
                        &KV[4 + tt][0] + c * 512);
        }
    }

#pragma unroll
    for (int t = 0; t < 16; t++) {
        const int sl = t & 3;
        const int par = t & 1;
        if (t < 15) {
            wait_vmcnt<4>();   // tile t's 4 loads landed; later tiles in flight
        } else {
            wait_vmcnt<0>();
        }
        barrier_raw();
        // prefetch AFTER barrier: max V-slot read distance among waves is t-1,
        // (t+2)-(t-1)=3 < 4 slots -> race-free with T15's extended reads.
        if (t < 14) {
            const int ds = (t + 2) & 3;
            int kv0 = (t + 2) * 64;
#pragma unroll
            for (int i = 0; i < 2; i++) {
                int c = w * 2 + i;
                int r = c * 8 + srow;
                gload_lds16(Kbase + (size_t)(kv0 + r) * HD_ + scol8 * 8,
                            &KV[ds][0] + c * 512);
                gload_lds16(Vbase + (size_t)r * T_ + kv0 + scol8 * 8,
                            &KV[4 + ds][0] + c * 512);
            }
        }

        // QK(t): S^T[k][q] (x log2e), col q = l31
        f32x16 sT0, sT1;
        __builtin_amdgcn_s_setprio(1);
        {
            short8 ka0 = *(const short8*)(kv + sl * 4096 + rowlo + fofs[0]);
            short8 ka1 = *(const short8*)(kv + sl * 4096 + 2048 + rowlo + fofs[0]);
            sT0 = __builtin_amdgcn_mfma_f32_32x32x16_bf16(ka0, qa[0], z16, 0, 0, 0);
            sT1 = __builtin_amdgcn_mfma_f32_32x32x16_bf16(ka1, qa[0], z16, 0, 0, 0);
        }
#pragma unroll
        for (int s = 1; s < 4; s++) {
            short8 ka0 = *(const short8*)(kv + sl * 4096 + rowlo + fofs[s]);
            short8 ka1 = *(const short8*)(kv + sl * 4096 + 2048 + rowlo + fofs[s]);
            sT0 = __builtin_amdgcn_mfma_f32_32x32x16_bf16(ka0, qa[s], sT0, 0, 0, 0);
            sT1 = __builtin_amdgcn_mfma_f32_32x32x16_bf16(ka1, qa[s], sT1, 0, 0, 0);
        }
        __builtin_amdgcn_s_setprio(0);

        // PV(t-1): overlaps the exp/pack below (separate pipes, same wave)
        if (t == 1 || t == 3 || t == 5 || t == 7 || t == 9 || t == 11 || t == 13 || t == 15) {
            PV_BLOCK(pk0[0], pk1[0], (t - 1) & 3)
        } else if (t > 0) {
            PV_BLOCK(pk0[1], pk1[1], (t - 1) & 3)
        }

        // exp/pack(t) into parity bank par
#pragma unroll
        for (int i = 0; i < 8; i++) {
            pk0[par][i] = pack2bf(__builtin_amdgcn_exp2f(sT0[2 * i]),
                                  __builtin_amdgcn_exp2f(sT0[2 * i + 1]));
            pk1[par][i] = pack2bf(__builtin_amdgcn_exp2f(sT1[2 * i]),
                                  __builtin_amdgcn_exp2f(sT1[2 * i + 1]));
        }
    }

    // final PV for tile 15 (parity 1, V slot 3 — stable, all loads drained)
    PV_BLOCK(pk0[1], pk1[1], 3)
#undef PV_BLOCK

#pragma unroll
    for (int r = 0; r < 16; r++) {
        float li = 1.0f / __shfl(o5[r], hi * 32);
        int qr = (r & 3) + 8 * (r >> 2) + 4 * hi;
        int trow = q0 + w * 32 + qr;
        size_t base = ((size_t)b * T_ + trow) * C_ + h * HD_;
        Y[base + l31] = f2bf(o0[r] * li);
        Y[base + 32 + l31] = f2bf(o1[r] * li);
    }
}

// ---------------- K3: O projection + bias + residual, out (B,C,T) fp32 ----------------
__global__ __launch_bounds__(256) void k_oproj(const ushort* __restrict__ Y,
                                               const ushort* __restrict__ Wot,
                                               const float* __restrict__ bo,
                                               const float* __restrict__ x,
                                               float* __restrict__ out) {
    __shared__ __align__(16) ushort As[2][8192];
    __shared__ __align__(16) ushort Bs[2][8192];
    f32x4 acc[4][4];
    int tid = threadIdx.x;
    int L = blockIdx.x;
    int n = L >> 3, xcd = L & 7;
    int row0 = (xcd * 8 + (n & 7)) * 128;
    int col0 = (n >> 3) * 128;
    gemm_core(Y, Wot, row0, col0, tid, As, Bs, acc);
    int lane = tid & 63, w = tid >> 6;
    int wm = (w >> 1) * 64, wn = (w & 1) * 64;
#pragma unroll
    for (int mt = 0; mt < 4; mt++) {
        int grow0 = row0 + wm + mt * 16 + ((lane >> 4) << 2);
        int b = grow0 >> 10, t = grow0 & 1023;
#pragma unroll
        for (int nt = 0; nt < 4; nt++) {
            int c = col0 + wn + nt * 16 + (lane & 15);
            float bsv = bo[c];
            size_t off = ((size_t)b * C_ + c) * T_ + t;
            float4 xv = *(const float4*)(x + off);
            float4 ov;
            ov.x = acc[mt][nt][0] + xv.x + bsv;
            ov.y = acc[mt][nt][1] + xv.y + bsv;
            ov.z = acc[mt][nt][2] + xv.z + bsv;
            ov.w = acc[mt][nt][3] + xv.w + bsv;
            *(float4*)(out + off) = ov;
        }
    }
}

extern "C" void kernel_launch(void* const* d_in, const int* in_sizes, int n_in,
                              void* d_out, int out_size, void* d_ws, size_t ws_size,
                              hipStream_t stream) {
    const float* x  = (const float*)d_in[0];
    const float* Wq = (const float*)d_in[1];
    const float* bq = (const float*)d_in[2];
    const float* Wk = (const float*)d_in[3];
    const float* bk = (const float*)d_in[4];
    const float* Wv = (const float*)d_in[5];
    const float* bv = (const float*)d_in[6];
    const float* Wo = (const float*)d_in[7];
    const float* bo = (const float*)d_in[8];
    float* out = (float*)d_out;

    char* ws = (char*)d_ws;
    ushort* xt    = (ushort*)(ws + 0);          // 8 MB; reused as Y after K1
    ushort* Wqkvt = (ushort*)(ws + 8388608);
    ushort* Wot   = (ushort*)(ws + 9961472);
    ushort* Qh    = (ushort*)(ws + 10485760);
    ushort* Kh    = (ushort*)(ws + 18874368);
    ushort* Vt    = (ushort*)(ws + 27262976);
    ushort* Yw    = xt;

    k_prep<<<dim3(5120), 256, 0, stream>>>(x, Wq, Wk, Wv, Wo, xt, Wqkvt, Wot);
    k_qkv<<<dim3(768), 256, 0, stream>>>(xt, Wqkvt, bq, bk, bv, Qh, Kh, Vt);
    k_attn<<<dim3(512), 256, 0, stream>>>(Qh, Kh, Vt, Yw);
    k_oproj<<<dim3(256), 256, 0, stream>>>(Yw, Wot, bo, x, out);
}